// Round 2
// baseline (60671.771 us; speedup 1.0000x reference)
//
#include <hip/hip_runtime.h>
#include <hip/hip_bf16.h>

// DSDMSR_x8: 13-unit SRCNN cascade. Inputs/outputs fp32 (per reference dtypes).
// Fused per-unit tile kernel: conv9x9(1->64)+ReLU -> conv5x5(64->32)+ReLU -> conv5x5(32->1)
// entirely in LDS per 8x8 output tile (halo 8 -> 24x24 input tile).
// h1/h2 held in LDS as bf16 to fit the 64 KiB static-LDS cap (err ~0.5% << 2% threshold).
// Stage outputs land in d_out (fp32); later stages + MSF read d_out directly.

typedef unsigned short ushort_t;

__device__ __forceinline__ float us2f(ushort_t u) {
    return __uint_as_float(((unsigned int)u) << 16);
}
__device__ __forceinline__ ushort_t f2us(float f) {
    unsigned int x = __float_as_uint(f);
    unsigned int r = (x + 0x7fffu + ((x >> 16) & 1u)) >> 16;
    return (ushort_t)r;
}

// ---------------------------------------------------------------------------
// Fused SRCNN tile kernel. T=8 output tile, block=256 threads.
//   input tile : 24x24 (halo 8)  -> s_in (fp32,  2304 B)
//   w1 staged  : 64x81 fp32      -> s_w1 (20736 B)
//   h1         : 16x16 x 64ch    -> s_h1 (bf16, 32768 B)
//   h2         : 12x12 x 32ch    -> s_h2 (bf16,  9216 B)   total 65280 B
// ---------------------------------------------------------------------------
__global__ __launch_bounds__(256) void srcnn_tile(
    const float* __restrict__ in, int H, int W,
    const float* __restrict__ gW1, const float* __restrict__ gB1,
    const float* __restrict__ gW2, const float* __restrict__ gB2,
    const float* __restrict__ gW3, const float* __restrict__ gB3,
    int unit,
    float* __restrict__ out,
    int outW, int outH, int s2, int px, int py)
{
    __shared__ float    s_in[24 * 24];
    __shared__ float    s_w1[64 * 81];
    __shared__ float    s_b1[64];
    __shared__ ushort_t s_h1[64 * 256];   // [ch][y1*16+x1]
    __shared__ ushort_t s_h2[32 * 144];   // [co][y2*12+x2]

    const int t  = threadIdx.x;
    const int ox = blockIdx.x * 8;
    const int oy = blockIdx.y * 8;
    const int b  = blockIdx.z;

    const float* inb = in + (size_t)b * H * W;

    // ---- phase 0: stage input tile (zero-padded) + unit-1 weights ----
    for (int idx = t; idx < 576; idx += 256) {
        int y = idx / 24;
        int x = idx - y * 24;
        int gy = oy - 8 + y, gx = ox - 8 + x;
        float v = 0.f;
        if (gy >= 0 && gy < H && gx >= 0 && gx < W) v = inb[(size_t)gy * W + gx];
        s_in[idx] = v;
    }
    const float* w1u = gW1 + (size_t)unit * 5184;
    for (int idx = t; idx < 5184; idx += 256) s_w1[idx] = w1u[idx];
    if (t < 64) s_b1[t] = gB1[unit * 64 + t];
    __syncthreads();

    // ---- phase 1: h1 = relu(conv9x9(in)) over 16x16 x 64ch ----
    {
        int y1 = t >> 4, x1 = t & 15;
        int gy = oy - 4 + y1, gx = ox - 4 + x1;
        bool valid = (gy >= 0 && gy < H && gx >= 0 && gx < W);
        const float* ip0 = &s_in[y1 * 24 + x1];
        for (int ch = 0; ch < 64; ++ch) {
            float s = s_b1[ch];
            const float* wp = &s_w1[ch * 81];
#pragma unroll
            for (int dy = 0; dy < 9; ++dy) {
#pragma unroll
                for (int dx = 0; dx < 9; ++dx) {
                    s += ip0[dy * 24 + dx] * wp[dy * 9 + dx];
                }
            }
            s = valid ? fmaxf(s, 0.f) : 0.f;
            s_h1[ch * 256 + t] = f2us(s);
        }
    }
    __syncthreads();

    // ---- phase 2: h2 = relu(conv5x5(h1)) over 12x12 x 32ch ----
    // thread t: co = t>>3 (fixed output channel), g = t&7, 18 pixels each.
    {
        int co = t >> 3;
        int g  = t & 7;
        float acc[18];
        int   boff[18];
        float vmul[18];
#pragma unroll
        for (int j = 0; j < 18; ++j) {
            int pos = g * 18 + j;
            int y2 = pos / 12;
            int x2 = pos - y2 * 12;
            boff[j] = y2 * 16 + x2;
            int gy = oy - 2 + y2, gx = ox - 2 + x2;
            vmul[j] = (gy >= 0 && gy < H && gx >= 0 && gx < W) ? 1.f : 0.f;
            acc[j] = 0.f;
        }
        const float* w2u = gW2 + ((size_t)(unit * 32 + co)) * 64 * 25;
        for (int ci = 0; ci < 64; ++ci) {
            float w[25];
            const float* wp = w2u + ci * 25;
#pragma unroll
            for (int k = 0; k < 25; ++k) w[k] = wp[k];
            const ushort_t* hp0 = &s_h1[ci * 256];
#pragma unroll
            for (int j = 0; j < 18; ++j) {
                const ushort_t* hp = hp0 + boff[j];
                float a = acc[j];
#pragma unroll
                for (int dy = 0; dy < 5; ++dy) {
#pragma unroll
                    for (int dx = 0; dx < 5; ++dx) {
                        a += us2f(hp[dy * 16 + dx]) * w[dy * 5 + dx];
                    }
                }
                acc[j] = a;
            }
        }
        float bco = gB2[unit * 32 + co];
#pragma unroll
        for (int j = 0; j < 18; ++j) {
            s_h2[co * 144 + g * 18 + j] = f2us(fmaxf(acc[j] + bco, 0.f) * vmul[j]);
        }
    }
    __syncthreads();

    // ---- phase 3: out = conv5x5(h2, 32->1) over 8x8, write interleaved ----
    if (t < 64) {
        int y = t >> 3, x = t & 7;
        float s = gB3[unit];
        for (int ci = 0; ci < 32; ++ci) {
            const ushort_t* hp = &s_h2[ci * 144 + y * 12 + x];
            const float* wp = gW3 + (size_t)(unit * 32 + ci) * 25;
#pragma unroll
            for (int dy = 0; dy < 5; ++dy) {
#pragma unroll
                for (int dx = 0; dx < 5; ++dx) {
                    s += us2f(hp[dy * 12 + dx]) * wp[dy * 5 + dx];
                }
            }
        }
        int gy = oy + y, gx = ox + x;
        size_t o = (size_t)b * outW * outH + (size_t)(gy * s2 + py) * outW + (gx * s2 + px);
        out[o] = s;
    }
}

// ---------------------------------------------------------------------------
// MSF input: up4(out_x2) + up2(out_x4) + out_x8, read from d_out (fp32).
// jax.image.resize bilinear: half-pixel coords (i+0.5)/s - 0.5, clamped taps.
// ---------------------------------------------------------------------------
__device__ __forceinline__ void ax_w(int i, float inv_s, int n, int& i0, int& i1, float& w1) {
    float c  = (i + 0.5f) * inv_s - 0.5f;
    float fl = floorf(c);
    w1 = c - fl;
    int ii = (int)fl;
    i0 = ii < 0 ? 0 : ii;
    i1 = (ii + 1 >= n) ? (n - 1) : (ii + 1);
}

__global__ __launch_bounds__(256) void msf_in_kernel(
    const float* __restrict__ f2, const float* __restrict__ f4,
    const float* __restrict__ f8, float* __restrict__ dst)
{
    int idx = blockIdx.x * 256 + threadIdx.x;   // 4*512*512 exactly
    int x = idx & 511;
    int y = (idx >> 9) & 511;
    int b = idx >> 18;

    int y0, y1, x0, x1;
    float wy, wx;

    // up4 from 128x128
    ax_w(y, 0.25f, 128, y0, y1, wy);
    ax_w(x, 0.25f, 128, x0, x1, wx);
    const float* p2 = f2 + (size_t)b * 16384;
    float v4 = (1.f - wy) * ((1.f - wx) * p2[y0 * 128 + x0] + wx * p2[y0 * 128 + x1])
             +        wy  * ((1.f - wx) * p2[y1 * 128 + x0] + wx * p2[y1 * 128 + x1]);

    // up2 from 256x256
    ax_w(y, 0.5f, 256, y0, y1, wy);
    ax_w(x, 0.5f, 256, x0, x1, wx);
    const float* p4 = f4 + (size_t)b * 65536;
    float v2 = (1.f - wy) * ((1.f - wx) * p4[y0 * 256 + x0] + wx * p4[y0 * 256 + x1])
             +        wy  * ((1.f - wx) * p4[y1 * 256 + x0] + wx * p4[y1 * 256 + x1]);

    dst[idx] = v4 + v2 + f8[idx];
}

// ---------------------------------------------------------------------------
extern "C" void kernel_launch(void* const* d_in, const int* in_sizes, int n_in,
                              void* d_out, int out_size, void* d_ws, size_t ws_size,
                              hipStream_t stream)
{
    (void)in_sizes; (void)n_in; (void)out_size; (void)ws_size;

    const float* image = (const float*)d_in[0];
    const float* W1    = (const float*)d_in[1];
    const float* B1    = (const float*)d_in[2];
    const float* W2    = (const float*)d_in[3];
    const float* B2    = (const float*)d_in[4];
    const float* W3    = (const float*)d_in[5];
    const float* B3    = (const float*)d_in[6];

    float* out = (float*)d_out;
    float* o2 = out;                 // (4,1,128,128) = 65536
    float* o4 = out + 65536;         // (4,1,256,256) = 262144
    float* o8 = out + 327680;        // (4,1,512,512) = 1048576
    float* om = out + 1376256;       // msf (4,1,512,512)

    float* fm = (float*)d_ws;        // msf_in : 1048576 floats = 4 MB

    // stage x2: image (4,1,64,64) -> o2 (128x128), units 0..3
    for (int k = 0; k < 4; ++k) {
        srcnn_tile<<<dim3(8, 8, 4), 256, 0, stream>>>(
            image, 64, 64, W1, B1, W2, B2, W3, B3, k,
            o2, 128, 128, 2, k & 1, k >> 1);
    }
    // stage x4: o2 (128x128) -> o4 (256x256), units 4..7
    for (int k = 0; k < 4; ++k) {
        srcnn_tile<<<dim3(16, 16, 4), 256, 0, stream>>>(
            o2, 128, 128, W1, B1, W2, B2, W3, B3, 4 + k,
            o4, 256, 256, 2, k & 1, k >> 1);
    }
    // stage x8: o4 (256x256) -> o8 (512x512), units 8..11
    for (int k = 0; k < 4; ++k) {
        srcnn_tile<<<dim3(32, 32, 4), 256, 0, stream>>>(
            o4, 256, 256, W1, B1, W2, B2, W3, B3, 8 + k,
            o8, 512, 512, 2, k & 1, k >> 1);
    }
    // msf_in = up4(o2) + up2(o4) + o8
    msf_in_kernel<<<4096, 256, 0, stream>>>(o2, o4, o8, fm);

    // msf: unit 12 on fm (512x512), plain (non-interleaved) output
    srcnn_tile<<<dim3(64, 64, 4), 256, 0, stream>>>(
        fm, 512, 512, W1, B1, W2, B2, W3, B3, 12,
        om, 512, 512, 1, 0, 0);
}

// Round 3
// 3765.899 us; speedup vs baseline: 16.1108x; 16.1108x over previous
//
#include <hip/hip_runtime.h>

// DSDMSR_x8: 13-unit SRCNN cascade, fp32 I/O, bf16 MFMA compute.
// Per 12x12 output tile: conv9x9(1->64) as im2col GEMM (K=96 padded, 3 chunks),
// conv5x5(64->32) as 25 per-tap GEMMs (K=64, 2 chunks of 32), conv3 vector.
// mfma_f32_16x16x32_bf16 throughout. h1/h2 bf16 in LDS, pixel-major.
// LDS: sA (im2col -> h2) 32000 B, sB (s_in -> h1 chunk) 32000 B = 64000 B total.

typedef unsigned short ushort_t;
typedef __attribute__((ext_vector_type(8))) short short8;     // 8 bf16 (4 VGPRs)
typedef __attribute__((ext_vector_type(4))) float f32x4;      // 4 fp32 acc
typedef __attribute__((ext_vector_type(4))) unsigned int uint4v;

__device__ __forceinline__ float us2f(ushort_t u) {
    return __uint_as_float(((unsigned int)u) << 16);
}
__device__ __forceinline__ ushort_t f2us(float f) {
    unsigned int x = __float_as_uint(f);
    return (ushort_t)((x + 0x7fffu + ((x >> 16) & 1u)) >> 16);
}

#define MFMA16(a, b, c) __builtin_amdgcn_mfma_f32_16x16x32_bf16((a), (b), (c), 0, 0, 0)

// ---------------------------------------------------------------------------
// Weight prep: W1 (13,64,81) fp32 -> w1t bf16 [u*64+ch][96] (taps 81..95 = 0)
//              W2 (13,32,64,25) fp32 -> w2t bf16 [u][tap][co][ci]
// ---------------------------------------------------------------------------
__global__ __launch_bounds__(256) void prep_weights(
    const float* __restrict__ W1, const float* __restrict__ W2,
    ushort_t* __restrict__ w1t, ushort_t* __restrict__ w2t)
{
    int i = blockIdx.x * 256 + threadIdx.x;
    if (i < 13 * 64 * 96) {
        int kp = i % 96;
        int uc = i / 96;
        w1t[i] = (kp < 81) ? f2us(W1[uc * 81 + kp]) : (ushort_t)0;
    }
    if (i < 13 * 25 * 32 * 64) {
        int ci = i & 63;
        int r  = i >> 6;
        int co = r & 31;
        int ut = r >> 5;          // u*25 + tap
        int tap = ut % 25;
        int u   = ut / 25;
        w2t[i] = f2us(W2[(((u * 32 + co) * 64 + ci) * 25) + tap]);
    }
}

// ---------------------------------------------------------------------------
// Fused SRCNN MFMA tile kernel. 12x12 out tile, 256 threads (4 waves).
// h2: 16x16 (16 m-tiles), h1: 20x20 (25 m-tiles), in: 28x28.
// ---------------------------------------------------------------------------
__global__ __launch_bounds__(256, 2) void srcnn_mfma(
    const float* __restrict__ in, int H, int W,
    const ushort_t* __restrict__ w1t, const ushort_t* __restrict__ w2t,
    const float* __restrict__ gB1, const float* __restrict__ gB2,
    const float* __restrict__ gW3, const float* __restrict__ gB3,
    int unit, float* __restrict__ out,
    int outW, int outH, int s2, int ppx, int ppy)
{
    __shared__ __align__(16) ushort_t sA[400 * 40];   // im2col chunk -> h2 [px16x16][co32]
    __shared__ __align__(16) ushort_t sB[400 * 40];   // s_in (head, fp32) -> h1 chunk [px20x20][ci32]
    float* s_in = (float*)sB;

    const int t    = threadIdx.x;
    const int lane = t & 63;
    const int wv   = t >> 6;
    const int q    = lane >> 4;
    const int l15  = lane & 15;
    const int ox0  = blockIdx.x * 12;
    const int oy0  = blockIdx.y * 12;
    const int b    = blockIdx.z;

    const float* inb = in + (size_t)b * H * W;

    // ---- stage input 28x28 (origin -8, zero-padded) into sB head ----
    for (int idx = t; idx < 784; idx += 256) {
        int y = idx / 28, x = idx - 28 * y;
        int gy = oy0 - 8 + y, gx = ox0 - 8 + x;
        float v = 0.f;
        if (gy >= 0 && gy < H && gx >= 0 && gx < W) v = inb[(size_t)gy * W + gx];
        s_in[idx] = v;
    }
    __syncthreads();

    // ================= conv1: im2col GEMM, K = 96 (3 chunks of 32) =========
    // wave wv owns m-tiles {wv, wv+4, ...} (25 tiles over 400 h1 px), all 4 n-tiles (64 ch)
    f32x4 acc1[7][4];
#pragma unroll
    for (int i = 0; i < 7; ++i)
#pragma unroll
        for (int n = 0; n < 4; ++n) acc1[i][n] = (f32x4){0.f, 0.f, 0.f, 0.f};

    const ushort_t* w1u = w1t + (size_t)unit * 64 * 96;

    for (int kc = 0; kc < 3; ++kc) {
        // build im2col chunk (taps kc*32 .. kc*32+31) into sA [px][32], stride 40
        for (int g = t; g < 1600; g += 256) {          // 400 px * 4 groups of 8 taps
            int px = g >> 2, kg = g & 3;
            int py1 = (px * 205) >> 12;                // px / 20
            int px1 = px - py1 * 20;
            int kb = kc * 32 + kg * 8;
            __align__(16) ushort_t tmp[8];
#pragma unroll
            for (int j = 0; j < 8; ++j) {
                int tap = kb + j;
                float v = 0.f;
                if (tap < 81) {
                    int ty = (tap * 57) >> 9;          // tap / 9
                    int tx = tap - ty * 9;
                    v = s_in[(py1 + ty) * 28 + px1 + tx];
                }
                tmp[j] = f2us(v);
            }
            *(uint4v*)&sA[px * 40 + kg * 8] = *(const uint4v*)tmp;
        }
        __syncthreads();

        short8 bf[4];
#pragma unroll
        for (int n = 0; n < 4; ++n) {
            int ch = n * 16 + l15;
            bf[n] = *(const short8*)&w1u[ch * 96 + kc * 32 + q * 8];
        }
#pragma unroll
        for (int im = 0; im < 7; ++im) {
            int m = wv + im * 4; if (m > 24) m = 24;   // clamped dup, store-guarded
            short8 a = *(const short8*)&sA[(m * 16 + l15) * 40 + q * 8];
#pragma unroll
            for (int n = 0; n < 4; ++n)
                acc1[im][n] = MFMA16(a, bf[n], acc1[im][n]);
        }
        __syncthreads();
    }

    // ================= conv2: 25 per-tap GEMMs, K = 64 (2 ci-chunks) ========
    // wave wv owns h2 rows wv*4..wv*4+3 (16 m-tiles = 16 rows), both n-tiles (32 co)
    f32x4 acc2[4][2];
#pragma unroll
    for (int i = 0; i < 4; ++i) { acc2[i][0] = (f32x4){0.f,0.f,0.f,0.f}; acc2[i][1] = (f32x4){0.f,0.f,0.f,0.f}; }

    const ushort_t* w2u = w2t + (size_t)unit * 25 * 32 * 64;

    for (int chunk = 0; chunk < 2; ++chunk) {
        // ---- write h1 ci-chunk (32 ch) from conv1 C-frags into sB ----
        // C layout: col = lane&15 (ch), row = q*4 + reg (px within tile)
#pragma unroll
        for (int im = 0; im < 7; ++im) {
            int m = wv + im * 4;
            if (m < 25) {
#pragma unroll
                for (int nn = 0; nn < 2; ++nn) {
                    int n  = chunk * 2 + nn;
                    int ci = n * 16 + l15;
                    float bias = gB1[unit * 64 + ci];
#pragma unroll
                    for (int r = 0; r < 4; ++r) {
                        int px  = m * 16 + q * 4 + r;          // 0..399
                        int py1 = (px * 205) >> 12;
                        int px1 = px - py1 * 20;
                        int gy = oy0 - 4 + py1, gx = ox0 - 4 + px1;
                        float v = fmaxf(acc1[im][n][r] + bias, 0.f);
                        if (!(gy >= 0 && gy < H && gx >= 0 && gx < W)) v = 0.f;
                        sB[px * 40 + nn * 16 + l15] = f2us(v);
                    }
                }
            }
        }
        __syncthreads();

        // ---- MFMA over 25 taps, B prefetched one tap ahead ----
        short8 b0 = *(const short8*)&w2u[(0 * 32 + l15) * 64 + chunk * 32 + q * 8];
        short8 b1 = *(const short8*)&w2u[(0 * 32 + 16 + l15) * 64 + chunk * 32 + q * 8];
        for (int tap = 0; tap < 25; ++tap) {
            short8 nb0 = b0, nb1 = b1;
            if (tap < 24) {
                nb0 = *(const short8*)&w2u[((tap + 1) * 32 + l15) * 64 + chunk * 32 + q * 8];
                nb1 = *(const short8*)&w2u[((tap + 1) * 32 + 16 + l15) * 64 + chunk * 32 + q * 8];
            }
            int dy = (tap * 13) >> 6;                  // tap / 5
            int dx = tap - 5 * dy;
#pragma unroll
            for (int im = 0; im < 4; ++im) {
                int hy  = wv * 4 + im;
                int lin = (hy + dy) * 20 + l15 + dx;
                short8 a = *(const short8*)&sB[lin * 40 + q * 8];
                acc2[im][0] = MFMA16(a, b0, acc2[im][0]);
                acc2[im][1] = MFMA16(a, b1, acc2[im][1]);
            }
            b0 = nb0; b1 = nb1;
        }
        __syncthreads();
    }

    // ---- write h2 [px16x16][co32] into sA (im2col dead) ----
#pragma unroll
    for (int im = 0; im < 4; ++im) {
        int m = wv * 4 + im;
#pragma unroll
        for (int n = 0; n < 2; ++n) {
            int co = n * 16 + l15;
            float bias = gB2[unit * 32 + co];
#pragma unroll
            for (int r = 0; r < 4; ++r) {
                int px = m * 16 + q * 4 + r;
                int hy = px >> 4, hx = px & 15;
                int gy = oy0 - 2 + hy, gx = ox0 - 2 + hx;
                float v = fmaxf(acc2[im][n][r] + bias, 0.f);
                if (!(gy >= 0 && gy < H && gx >= 0 && gx < W)) v = 0.f;
                sA[px * 32 + co] = f2us(v);
            }
        }
    }
    __syncthreads();

    // ================= conv3: 5x5, 32->1, vector, 144 threads ===============
    if (t < 144) {
        int oy2 = (t * 683) >> 13;                     // t / 12
        int ox2 = t - 12 * oy2;
        const float* w3u = gW3 + unit * 800;
        float s = gB3[unit];
        for (int cg = 0; cg < 4; ++cg) {
#pragma unroll
            for (int dy = 0; dy < 5; ++dy) {
#pragma unroll
                for (int dx = 0; dx < 5; ++dx) {
                    short8 h = *(const short8*)&sA[((oy2 + dy) * 16 + ox2 + dx) * 32 + cg * 8];
#pragma unroll
                    for (int e = 0; e < 8; ++e) {
                        s += us2f((ushort_t)h[e]) * w3u[(cg * 8 + e) * 25 + dy * 5 + dx];
                    }
                }
            }
        }
        int gy = oy0 + oy2, gx = ox0 + ox2;
        if (gy < H && gx < W) {
            size_t o = (size_t)b * outW * outH + (size_t)(gy * s2 + ppy) * outW + (gx * s2 + ppx);
            out[o] = s;
        }
    }
}

// ---------------------------------------------------------------------------
// MSF input: up4(out_x2) + up2(out_x4) + out_x8 (bilinear, half-pixel, clamped)
// ---------------------------------------------------------------------------
__device__ __forceinline__ void ax_w(int i, float inv_s, int n, int& i0, int& i1, float& w1) {
    float c  = (i + 0.5f) * inv_s - 0.5f;
    float fl = floorf(c);
    w1 = c - fl;
    int ii = (int)fl;
    i0 = ii < 0 ? 0 : ii;
    i1 = (ii + 1 >= n) ? (n - 1) : (ii + 1);
}

__global__ __launch_bounds__(256) void msf_in_kernel(
    const float* __restrict__ f2, const float* __restrict__ f4,
    const float* __restrict__ f8, float* __restrict__ dst)
{
    int idx = blockIdx.x * 256 + threadIdx.x;   // 4*512*512 exactly
    int x = idx & 511;
    int y = (idx >> 9) & 511;
    int b = idx >> 18;

    int y0, y1, x0, x1;
    float wy, wx;

    ax_w(y, 0.25f, 128, y0, y1, wy);
    ax_w(x, 0.25f, 128, x0, x1, wx);
    const float* p2 = f2 + (size_t)b * 16384;
    float v4 = (1.f - wy) * ((1.f - wx) * p2[y0 * 128 + x0] + wx * p2[y0 * 128 + x1])
             +        wy  * ((1.f - wx) * p2[y1 * 128 + x0] + wx * p2[y1 * 128 + x1]);

    ax_w(y, 0.5f, 256, y0, y1, wy);
    ax_w(x, 0.5f, 256, x0, x1, wx);
    const float* p4 = f4 + (size_t)b * 65536;
    float v2 = (1.f - wy) * ((1.f - wx) * p4[y0 * 256 + x0] + wx * p4[y0 * 256 + x1])
             +        wy  * ((1.f - wx) * p4[y1 * 256 + x0] + wx * p4[y1 * 256 + x1]);

    dst[idx] = v4 + v2 + f8[idx];
}

// ---------------------------------------------------------------------------
extern "C" void kernel_launch(void* const* d_in, const int* in_sizes, int n_in,
                              void* d_out, int out_size, void* d_ws, size_t ws_size,
                              hipStream_t stream)
{
    (void)in_sizes; (void)n_in; (void)out_size; (void)ws_size;

    const float* image = (const float*)d_in[0];
    const float* W1    = (const float*)d_in[1];
    const float* B1    = (const float*)d_in[2];
    const float* W2    = (const float*)d_in[3];
    const float* B2    = (const float*)d_in[4];
    const float* W3    = (const float*)d_in[5];
    const float* B3    = (const float*)d_in[6];

    float* out = (float*)d_out;
    float* o2 = out;                 // (4,1,128,128)
    float* o4 = out + 65536;         // (4,1,256,256)
    float* o8 = out + 327680;        // (4,1,512,512)
    float* om = out + 1376256;       // msf (4,1,512,512)

    float*    fm  = (float*)d_ws;                          // 1,048,576 f32 = 4 MB
    ushort_t* w1t = (ushort_t*)((char*)d_ws + (4u << 20)); // 13*64*96 bf16
    ushort_t* w2t = w1t + 13 * 64 * 96;                    // 13*25*32*64 bf16

    prep_weights<<<2600, 256, 0, stream>>>(W1, W2, w1t, w2t);

    for (int k = 0; k < 4; ++k) {
        srcnn_mfma<<<dim3(6, 6, 4), 256, 0, stream>>>(
            image, 64, 64, w1t, w2t, B1, B2, W3, B3, k,
            o2, 128, 128, 2, k & 1, k >> 1);
    }
    for (int k = 0; k < 4; ++k) {
        srcnn_mfma<<<dim3(11, 11, 4), 256, 0, stream>>>(
            o2, 128, 128, w1t, w2t, B1, B2, W3, B3, 4 + k,
            o4, 256, 256, 2, k & 1, k >> 1);
    }
    for (int k = 0; k < 4; ++k) {
        srcnn_mfma<<<dim3(22, 22, 4), 256, 0, stream>>>(
            o4, 256, 256, w1t, w2t, B1, B2, W3, B3, 8 + k,
            o8, 512, 512, 2, k & 1, k >> 1);
    }
    msf_in_kernel<<<4096, 256, 0, stream>>>(o2, o4, o8, fm);

    srcnn_mfma<<<dim3(43, 43, 4), 256, 0, stream>>>(
        fm, 512, 512, w1t, w2t, B1, B2, W3, B3, 12,
        om, 512, 512, 1, 0, 0);
}

// Round 4
// 2127.885 us; speedup vs baseline: 28.5127x; 1.7698x over previous
//
#include <hip/hip_runtime.h>

// DSDMSR_x8: 13-unit SRCNN cascade, fp32 I/O, bf16 MFMA compute.
// Per 12x12 output tile (256 thr / 4 waves, 2 blocks/CU):
//   conv1 9x9 1->64 : A-frags built in registers from s_in (no im2col), B in VGPRs
//   conv2 5x5 64->32: 25 per-tap GEMMs, K=64 in 2 ci-chunks; B staged via
//                     global_load_lds into a double-buffered 6-tap LDS ring
//   conv3 5x5 32->1 : per-tap MFMA (K=32), B broadcast from LDS, col 0 of C stored
// LDS 54336 B: h1 [cig4][px400][8] 25600 | ring 2x12288 / h2 [cog4][px256][8] | s_in/w3

typedef unsigned short ushort_t;
typedef __attribute__((ext_vector_type(8))) short short8;   // 8 bf16
typedef __attribute__((ext_vector_type(4))) float f32x4;

__device__ __forceinline__ float us2f(ushort_t u) { return __uint_as_float(((unsigned int)u) << 16); }
__device__ __forceinline__ ushort_t f2us(float f) {
    unsigned int x = __float_as_uint(f);
    return (ushort_t)((x + 0x7fffu + ((x >> 16) & 1u)) >> 16);
}

#define MFMA16(a, b, c) __builtin_amdgcn_mfma_f32_16x16x32_bf16((a), (b), (c), 0, 0, 0)

__device__ __forceinline__ void load_lds16(const void* gsrc, void* ldst) {
    __builtin_amdgcn_global_load_lds(
        (const __attribute__((address_space(1))) unsigned int*)gsrc,
        (__attribute__((address_space(3))) unsigned int*)ldst, 16, 0, 0);
}

// ---------------------------------------------------------------------------
// Weight prep (bf16, MFMA-fragment-friendly layouts):
//  w1t [u][kc3][cig4][ch64][8]  (k = kc*32+cig*8+e, zero for k>=81)
//  w2t [u][c2][tap25][cig4][co32][8]  (ci = c*32+cig*8+e)
//  w3t [u][tap25][ci32]
// ---------------------------------------------------------------------------
__global__ __launch_bounds__(256) void prep_weights(
    const float* __restrict__ W1, const float* __restrict__ W2, const float* __restrict__ W3,
    ushort_t* __restrict__ w1t, ushort_t* __restrict__ w2t, ushort_t* __restrict__ w3t)
{
    int i = blockIdx.x * 256 + threadIdx.x;
    if (i < 13 * 3 * 4 * 64 * 8) {           // 79872
        int e = i & 7, ch = (i >> 3) & 63, cig = (i >> 9) & 3;
        int r = i >> 11;                     // u*3 + kc
        int kc = r % 3, u = r / 3;
        int k = kc * 32 + cig * 8 + e;
        w1t[i] = (k < 81) ? f2us(W1[(u * 64 + ch) * 81 + k]) : (ushort_t)0;
    }
    if (i < 665600) {                        // 13*2*25*4*32*8
        int e = i & 7, co = (i >> 3) & 31, cig = (i >> 8) & 3;
        int r = i >> 10;                     // (u*2+c)*25 + tap
        int tap = r % 25, s = r / 25;
        int c = s & 1, u = s >> 1;
        int ci = c * 32 + cig * 8 + e;
        w2t[i] = f2us(W2[((u * 32 + co) * 64 + ci) * 25 + tap]);
    }
    if (i < 13 * 25 * 32) {                  // 10400
        int ci = i & 31, r = i >> 5;
        int tap = r % 25, u = r / 25;
        w3t[i] = f2us(W3[(u * 32 + ci) * 25 + tap]);
    }
}

// ---------------------------------------------------------------------------
__global__ __launch_bounds__(256, 2) void srcnn_mfma(
    const float* __restrict__ in, int H, int W,
    const ushort_t* __restrict__ w1t, const ushort_t* __restrict__ w2t,
    const ushort_t* __restrict__ w3t,
    const float* __restrict__ gB1, const float* __restrict__ gB2,
    const float* __restrict__ gB3,
    int unitBase, float* __restrict__ out, int s2)
{
    __shared__ __align__(16) char smem[54336];
    ushort_t* sH1 = (ushort_t*)smem;              // [cig4][px400][8]  25600 B
    char*     sX  = smem + 25600;                 // ring 2x12288 | h2 16384
    float*    sIn = (float*)(smem + 51200);       // 784 f32 (conv1 only)
    ushort_t* sW3 = (ushort_t*)(smem + 51200);    // 800 u16 (after conv1)

    const int t = threadIdx.x, lane = t & 63, wv = t >> 6;
    const int q = lane >> 4, l15 = lane & 15;
    const int z = blockIdx.z;
    const int k4 = (s2 == 2) ? (z >> 2) : 0;
    const int b  = (s2 == 2) ? (z & 3)  : z;
    const int unit = unitBase + k4;
    const int ppx = k4 & 1, ppy = k4 >> 1;
    const int ox0 = blockIdx.x * 12, oy0 = blockIdx.y * 12;
    const int outW = W * s2;
    const int outH = H * s2;
    const float* inb = in + (size_t)b * H * W;

    // conv1 B-fragments -> registers (12 x 16 B)
    short8 bf1[3][4];
    {
        const ushort_t* w1u = w1t + (size_t)unit * (3 * 4 * 64 * 8);
#pragma unroll
        for (int kc = 0; kc < 3; ++kc)
#pragma unroll
            for (int n = 0; n < 4; ++n)
                bf1[kc][n] = *(const short8*)&w1u[((kc * 4 + q) * 64 + (n * 16 + l15)) * 8];
    }

    const char* w2u = (const char*)w2t + (size_t)unit * 102400;

    // ring stage: step p covers taps of chunk c=p/5, group g=p%5 (6,6,6,6,1)
    auto stageW2 = [&](int p) {
        int c = p / 5, g = p - 5 * c;
        int t0 = g * 6;
        int nt = (t0 + 6 <= 25) ? 6 : (25 - t0);
        int nI = nt * 2;                       // 1024-B issues
        const char* src = w2u + (size_t)c * 51200 + (size_t)t0 * 2048;
        char* dst = sX + (p & 1) * 12288;
        for (int i = wv; i < nI; i += 4)
            load_lds16(src + i * 1024 + lane * 16, dst + i * 1024);
    };
    stageW2(0);   // prefetch chunk0/group0 during input staging + conv1

    // stage input 28x28 (origin -8, zero-padded)
    for (int idx = t; idx < 784; idx += 256) {
        int y = idx / 28, x = idx - 28 * y;
        int gy = oy0 - 8 + y, gx = ox0 - 8 + x;
        sIn[idx] = (gy >= 0 && gy < H && gx >= 0 && gx < W) ? inb[(size_t)gy * W + gx] : 0.f;
    }
    __syncthreads();

    // ---- conv1: A built in-register from sIn, 25 m-tiles over 400 h1 px ----
    int toff[3][8];
#pragma unroll
    for (int kc = 0; kc < 3; ++kc)
#pragma unroll
        for (int j = 0; j < 8; ++j) {
            int k = kc * 32 + q * 8 + j;
            if (k < 81) { int ty = (k * 57) >> 9; toff[kc][j] = ty * 28 + (k - 9 * ty); }
            else toff[kc][j] = -1;
        }

    f32x4 acc1[7][4];
#pragma unroll
    for (int i = 0; i < 7; ++i)
#pragma unroll
        for (int n = 0; n < 4; ++n) acc1[i][n] = (f32x4){0.f, 0.f, 0.f, 0.f};

#pragma unroll
    for (int im = 0; im < 7; ++im) {
        int m = wv + im * 4; if (m > 24) m = 24;      // clamped dup, store-guarded
        int px = m * 16 + l15;                        // 0..399 (20x20 h1 grid)
        int py1 = (px * 205) >> 12;
        int base = py1 * 28 + (px - 20 * py1);
#pragma unroll
        for (int kc = 0; kc < 3; ++kc) {
            union { short8 v; ushort_t u[8]; } a;
#pragma unroll
            for (int j = 0; j < 8; ++j) {
                int o = toff[kc][j];
                a.u[j] = (o >= 0) ? f2us(sIn[base + o]) : (ushort_t)0;
            }
#pragma unroll
            for (int n = 0; n < 4; ++n)
                acc1[im][n] = MFMA16(a.v, bf1[kc][n], acc1[im][n]);
        }
    }

    // ---- conv2: 25 per-tap GEMMs, K=64 in 2 ci-chunks, ring-staged B ----
    f32x4 acc2[4][2];
#pragma unroll
    for (int i = 0; i < 4; ++i) { acc2[i][0] = (f32x4){0.f,0.f,0.f,0.f}; acc2[i][1] = (f32x4){0.f,0.f,0.f,0.f}; }

    for (int c = 0; c < 2; ++c) {
        // h1 writeback for ci-chunk c (bias+relu+SAME-pad mask), layout [cig][px][8]
#pragma unroll
        for (int im = 0; im < 7; ++im) {
            int m = wv + im * 4;
            if (m < 25) {
#pragma unroll
                for (int nn = 0; nn < 2; ++nn) {
                    int n = c * 2 + nn;
                    int ci = n * 16 + l15;
                    float bias = gB1[unit * 64 + ci];
                    int cig = (nn * 16 + l15) >> 3;
                    int e   = l15 & 7;
#pragma unroll
                    for (int r = 0; r < 4; ++r) {
                        int px = m * 16 + q * 4 + r;
                        int py1 = (px * 205) >> 12;
                        int px1 = px - 20 * py1;
                        int gy = oy0 - 4 + py1, gx = ox0 - 4 + px1;
                        float v = fmaxf(acc1[im][n][r] + bias, 0.f);
                        if (!(gy >= 0 && gy < H && gx >= 0 && gx < W)) v = 0.f;
                        sH1[(cig * 400 + px) * 8 + e] = f2us(v);
                    }
                }
            }
        }
        __syncthreads();
        if (c == 0) {   // stage w3 into sIn region (dead after conv1)
            const ushort_t* w3u = w3t + unit * 800;
            for (int i = t; i < 800; i += 256) sW3[i] = w3u[i];
        }

        for (int g = 0; g < 5; ++g) {
            int p = c * 5 + g;
            if (p < 9) stageW2(p + 1);
            int t0 = g * 6;
            int t1 = (t0 + 6 <= 25) ? t0 + 6 : 25;
            const ushort_t* ring = (const ushort_t*)(sX + (p & 1) * 12288);
            for (int tap = t0; tap < t1; ++tap) {
                int ti = tap - t0;
                int dy = (tap * 13) >> 6, dx = tap - 5 * dy;
                short8 b0 = *(const short8*)&ring[(ti * 4 + q) * 256 + l15 * 8];
                short8 b1 = *(const short8*)&ring[(ti * 4 + q) * 256 + (16 + l15) * 8];
#pragma unroll
                for (int im = 0; im < 4; ++im) {
                    int hy = wv * 4 + im;
                    int h1px = (hy + dy) * 20 + l15 + dx;
                    short8 a = *(const short8*)&sH1[(q * 400 + h1px) * 8];
                    acc2[im][0] = MFMA16(a, b0, acc2[im][0]);
                    acc2[im][1] = MFMA16(a, b1, acc2[im][1]);
                }
            }
            __syncthreads();
        }
    }

    // ---- h2 writeback [cog4][px256][8] into sX (ring dead) ----
    ushort_t* sH2 = (ushort_t*)sX;
#pragma unroll
    for (int im = 0; im < 4; ++im) {
        int hy = wv * 4 + im;
#pragma unroll
        for (int n = 0; n < 2; ++n) {
            int co = n * 16 + l15;
            float bias = gB2[unit * 32 + co];
            int cog = co >> 3, e = co & 7;
#pragma unroll
            for (int r = 0; r < 4; ++r) {
                int hx = q * 4 + r;
                int gy = oy0 - 2 + hy, gx = ox0 - 2 + hx;
                float v = fmaxf(acc2[im][n][r] + bias, 0.f);
                if (!(gy >= 0 && gy < H && gx >= 0 && gx < W)) v = 0.f;
                sH2[(cog * 256 + hy * 16 + hx) * 8 + e] = f2us(v);
            }
        }
    }
    __syncthreads();

    // ---- conv3: per-tap MFMA, K=32, B broadcast; 9 m-tiles over 144 out px ----
    float b3 = gB3[unit];
    int nm = (wv == 0) ? 3 : 2;
    for (int jm = 0; jm < nm; ++jm) {
        int mt = wv + 4 * jm;                        // 0..8
        int p = mt * 16 + l15;                       // 0..143
        int oy2 = (p * 683) >> 13, ox2 = p - 12 * oy2;
        f32x4 acc = (f32x4){0.f, 0.f, 0.f, 0.f};
        for (int tap = 0; tap < 25; ++tap) {
            int dy = (tap * 13) >> 6, dx = tap - 5 * dy;
            int h2px = (oy2 + dy) * 16 + ox2 + dx;
            short8 a = *(const short8*)&sH2[(q * 256 + h2px) * 8];
            short8 w = *(const short8*)&sW3[tap * 32 + q * 8];
            acc = MFMA16(a, w, acc);
        }
        if (l15 == 0) {
#pragma unroll
            for (int r = 0; r < 4; ++r) {
                int pp = mt * 16 + q * 4 + r;
                int oy = (pp * 683) >> 13, ox = pp - 12 * oy;
                int gy = oy0 + oy, gx = ox0 + ox;
                if (gy < H && gx < W) {
                    size_t o = (size_t)b * outW * outH + (size_t)(gy * s2 + ppy) * outW + (gx * s2 + ppx);
                    out[o] = acc[r] + b3;
                }
            }
        }
    }
}

// ---------------------------------------------------------------------------
// MSF input: up4(out_x2) + up2(out_x4) + out_x8 (bilinear, half-pixel, clamped)
// ---------------------------------------------------------------------------
__device__ __forceinline__ void ax_w(int i, float inv_s, int n, int& i0, int& i1, float& w1) {
    float c  = (i + 0.5f) * inv_s - 0.5f;
    float fl = floorf(c);
    w1 = c - fl;
    int ii = (int)fl;
    i0 = ii < 0 ? 0 : ii;
    i1 = (ii + 1 >= n) ? (n - 1) : (ii + 1);
}

__global__ __launch_bounds__(256) void msf_in_kernel(
    const float* __restrict__ f2, const float* __restrict__ f4,
    const float* __restrict__ f8, float* __restrict__ dst)
{
    int idx = blockIdx.x * 256 + threadIdx.x;   // 4*512*512
    int x = idx & 511;
    int y = (idx >> 9) & 511;
    int b = idx >> 18;

    int y0, y1, x0, x1;
    float wy, wx;

    ax_w(y, 0.25f, 128, y0, y1, wy);
    ax_w(x, 0.25f, 128, x0, x1, wx);
    const float* p2 = f2 + (size_t)b * 16384;
    float v4 = (1.f - wy) * ((1.f - wx) * p2[y0 * 128 + x0] + wx * p2[y0 * 128 + x1])
             +        wy  * ((1.f - wx) * p2[y1 * 128 + x0] + wx * p2[y1 * 128 + x1]);

    ax_w(y, 0.5f, 256, y0, y1, wy);
    ax_w(x, 0.5f, 256, x0, x1, wx);
    const float* p4 = f4 + (size_t)b * 65536;
    float v2 = (1.f - wy) * ((1.f - wx) * p4[y0 * 256 + x0] + wx * p4[y0 * 256 + x1])
             +        wy  * ((1.f - wx) * p4[y1 * 256 + x0] + wx * p4[y1 * 256 + x1]);

    dst[idx] = v4 + v2 + f8[idx];
}

// ---------------------------------------------------------------------------
extern "C" void kernel_launch(void* const* d_in, const int* in_sizes, int n_in,
                              void* d_out, int out_size, void* d_ws, size_t ws_size,
                              hipStream_t stream)
{
    (void)in_sizes; (void)n_in; (void)out_size; (void)ws_size;

    const float* image = (const float*)d_in[0];
    const float* W1    = (const float*)d_in[1];
    const float* B1    = (const float*)d_in[2];
    const float* W2    = (const float*)d_in[3];
    const float* B2    = (const float*)d_in[4];
    const float* W3    = (const float*)d_in[5];
    const float* B3    = (const float*)d_in[6];

    float* out = (float*)d_out;
    float* o2 = out;                 // (4,1,128,128)
    float* o4 = out + 65536;         // (4,1,256,256)
    float* o8 = out + 327680;        // (4,1,512,512)
    float* om = out + 1376256;       // msf (4,1,512,512)

    float*    fm  = (float*)d_ws;                              // 4 MB
    ushort_t* w1t = (ushort_t*)((char*)d_ws + 4194304);        // 79872 u16
    ushort_t* w2t = (ushort_t*)((char*)d_ws + 4354048);        // 665600 u16
    ushort_t* w3t = (ushort_t*)((char*)d_ws + 5685248);        // 10400 u16

    prep_weights<<<2600, 256, 0, stream>>>(W1, W2, W3, w1t, w2t, w3t);

    srcnn_mfma<<<dim3(6, 6, 16), 256, 0, stream>>>(
        image, 64, 64, w1t, w2t, w3t, B1, B2, B3, 0, o2, 2);
    srcnn_mfma<<<dim3(11, 11, 16), 256, 0, stream>>>(
        o2, 128, 128, w1t, w2t, w3t, B1, B2, B3, 4, o4, 2);
    srcnn_mfma<<<dim3(22, 22, 16), 256, 0, stream>>>(
        o4, 256, 256, w1t, w2t, w3t, B1, B2, B3, 8, o8, 2);
    msf_in_kernel<<<4096, 256, 0, stream>>>(o2, o4, o8, fm);
    srcnn_mfma<<<dim3(43, 43, 4), 256, 0, stream>>>(
        fm, 512, 512, w1t, w2t, w3t, B1, B2, B3, 12, om, 1);
}

// Round 5
// 2089.060 us; speedup vs baseline: 29.0426x; 1.0186x over previous
//
#include <hip/hip_runtime.h>

// DSDMSR_x8: 13-unit SRCNN cascade, fp32 I/O, bf16 MFMA compute.
// Per 12x12 output tile (256 thr / 4 waves, 2 blocks/CU):
//   conv1 9x9 1->64 : A-frags built in registers from sIn, B in VGPRs
//   conv2 5x5 64->32: dx-major tap groups (5 taps each), K=64 in 2 ci-chunks;
//                     B staged global->VGPR->LDS ring (double-buffered, 1-group
//                     prefetch distance); A row-reuse across dy within a group
//   conv3 5x5 32->1 : per-tap MFMA (K=32), col 0 of C stored
// LDS 49344 B: sH1 4x(3200+16pad)sh | ring 2x10240 (union h2 4x(2048+16)sh) | sIn/sW3

typedef unsigned short ushort_t;
typedef __attribute__((ext_vector_type(8))) short short8;   // 8 bf16
typedef __attribute__((ext_vector_type(4))) float f32x4;
typedef __attribute__((ext_vector_type(4))) unsigned int uint4v;

__device__ __forceinline__ float us2f(ushort_t u) { return __uint_as_float(((unsigned int)u) << 16); }
__device__ __forceinline__ ushort_t f2us(float f) {
    unsigned int x = __float_as_uint(f);
    return (ushort_t)((x + 0x7fffu + ((x >> 16) & 1u)) >> 16);
}

#define MFMA16(a, b, c) __builtin_amdgcn_mfma_f32_16x16x32_bf16((a), (b), (c), 0, 0, 0)

// ---------------------------------------------------------------------------
// Weight prep (bf16, MFMA-fragment-friendly layouts):
//  w1t [u][kc3][cig4][ch64][8]          (k = kc*32+cig*8+e, zero for k>=81)
//  w2t [u][c2][dx5][dy5][cig4][co32][8] (ci = c*32+cig*8+e, tap = dy*5+dx)
//  w3t [u][tap25][ci32]
// ---------------------------------------------------------------------------
__global__ __launch_bounds__(256) void prep_weights(
    const float* __restrict__ W1, const float* __restrict__ W2, const float* __restrict__ W3,
    ushort_t* __restrict__ w1t, ushort_t* __restrict__ w2t, ushort_t* __restrict__ w3t)
{
    int i = blockIdx.x * 256 + threadIdx.x;
    if (i < 13 * 3 * 4 * 64 * 8) {           // 79872
        int e = i & 7, ch = (i >> 3) & 63, cig = (i >> 9) & 3;
        int r = i >> 11;                     // u*3 + kc
        int kc = r % 3, u = r / 3;
        int k = kc * 32 + cig * 8 + e;
        w1t[i] = (k < 81) ? f2us(W1[(u * 64 + ch) * 81 + k]) : (ushort_t)0;
    }
    if (i < 665600) {                        // 13*2*25*4*32*8
        int e = i & 7, co = (i >> 3) & 31, cig = (i >> 8) & 3;
        int r = i >> 10;                     // (u*2+c)*25 + s, s = dx*5+dy
        int s = r % 25, cc = r / 25;
        int dx = s / 5, dy = s - 5 * dx;
        int c = cc & 1, u = cc >> 1;
        int tap = dy * 5 + dx;
        int ci = c * 32 + cig * 8 + e;
        w2t[i] = f2us(W2[((u * 32 + co) * 64 + ci) * 25 + tap]);
    }
    if (i < 13 * 25 * 32) {                  // 10400
        int ci = i & 31, r = i >> 5;
        int tap = r % 25, u = r / 25;
        w3t[i] = f2us(W3[(u * 32 + ci) * 25 + tap]);
    }
}

// ---------------------------------------------------------------------------
__global__ __launch_bounds__(256, 2) void srcnn_mfma(
    const float* __restrict__ in, int H, int W,
    const ushort_t* __restrict__ w1t, const ushort_t* __restrict__ w2t,
    const ushort_t* __restrict__ w3t,
    const float* __restrict__ gB1, const float* __restrict__ gB2,
    const float* __restrict__ gB3,
    int unitBase, float* __restrict__ out, int s2)
{
    __shared__ __align__(16) char smem[49344];
    ushort_t* sH1  = (ushort_t*)smem;             // 4 planes x 3216 shorts (16-short skew pad)
    char*     sRing = smem + 25728;               // 2 x 10240 B  (union: h2 4 x 2064 shorts)
    float*    sIn  = (float*)(smem + 46208);      // 784 f32 (conv1 only)
    ushort_t* sW3  = (ushort_t*)(smem + 46208);   // 800 u16 (after conv1)
    ushort_t* sH2  = (ushort_t*)sRing;

    const int t = threadIdx.x, lane = t & 63, wv = t >> 6;
    const int q = lane >> 4, l15 = lane & 15;
    const int z = blockIdx.z;
    const int k4 = (s2 == 2) ? (z >> 2) : 0;
    const int b  = (s2 == 2) ? (z & 3)  : z;
    const int unit = unitBase + k4;
    const int ppx = k4 & 1, ppy = k4 >> 1;
    const int ox0 = blockIdx.x * 12, oy0 = blockIdx.y * 12;
    const int outW = W * s2;
    const int outH = H * s2;
    const float* inb = in + (size_t)b * H * W;

    const char* w2u = (const char*)w2t + (size_t)unit * 102400;

    // --- conv2 B staging: global -> VGPR (pf) -> LDS ring slot p&1 ---
    uint4v pf[3];
    auto ldGroup = [&](int p) {
        if (p < 10) {
            const char* src = w2u + (size_t)p * 10240 + lane * 16;
#pragma unroll
            for (int j = 0; j < 3; ++j) {
                int ck = wv + j * 4;
                if (ck < 10) pf[j] = *(const uint4v*)(src + ck * 1024);
            }
        }
    };
    auto wrGroup = [&](int p) {
        if (p < 10) {
            char* dst = sRing + (p & 1) * 10240 + lane * 16;
#pragma unroll
            for (int j = 0; j < 3; ++j) {
                int ck = wv + j * 4;
                if (ck < 10) *(uint4v*)(dst + ck * 1024) = pf[j];
            }
        }
    };

    ldGroup(0);

    // conv1 B-fragments -> registers (12 x 16 B)
    short8 bf1[3][4];
    {
        const ushort_t* w1u = w1t + (size_t)unit * (3 * 4 * 64 * 8);
#pragma unroll
        for (int kc = 0; kc < 3; ++kc)
#pragma unroll
            for (int n = 0; n < 4; ++n)
                bf1[kc][n] = *(const short8*)&w1u[((kc * 4 + q) * 64 + (n * 16 + l15)) * 8];
    }

    // stage input 28x28 (origin -8, zero-padded)
    for (int idx = t; idx < 784; idx += 256) {
        int y = idx / 28, x = idx - 28 * y;
        int gy = oy0 - 8 + y, gx = ox0 - 8 + x;
        sIn[idx] = (gy >= 0 && gy < H && gx >= 0 && gx < W) ? inb[(size_t)gy * W + gx] : 0.f;
    }
    __syncthreads();

    // ---- conv1: A built in-register from sIn, 25 m-tiles over 400 h1 px ----
    int toff[3][8];
#pragma unroll
    for (int kc = 0; kc < 3; ++kc)
#pragma unroll
        for (int j = 0; j < 8; ++j) {
            int k = kc * 32 + q * 8 + j;
            if (k < 81) { int ty = (k * 57) >> 9; toff[kc][j] = ty * 28 + (k - 9 * ty); }
            else toff[kc][j] = -1;
        }

    f32x4 acc1[7][4];
#pragma unroll
    for (int i = 0; i < 7; ++i)
#pragma unroll
        for (int n = 0; n < 4; ++n) acc1[i][n] = (f32x4){0.f, 0.f, 0.f, 0.f};

#pragma unroll
    for (int im = 0; im < 7; ++im) {
        int m = wv + im * 4; if (m > 24) m = 24;      // clamped dup, store-guarded
        int px = m * 16 + l15;                        // 0..399 (20x20 h1 grid)
        int py1 = (px * 205) >> 12;
        int base = py1 * 28 + (px - 20 * py1);
#pragma unroll
        for (int kc = 0; kc < 3; ++kc) {
            union { short8 v; ushort_t u[8]; } a;
#pragma unroll
            for (int j = 0; j < 8; ++j) {
                int o = toff[kc][j];
                a.u[j] = (o >= 0) ? f2us(sIn[base + o]) : (ushort_t)0;
            }
#pragma unroll
            for (int n = 0; n < 4; ++n)
                acc1[im][n] = MFMA16(a.v, bf1[kc][n], acc1[im][n]);
        }
    }

    wrGroup(0);   // group 0 into ring slot 0 (loads issued before conv1)

    // ---- conv2: dx-major groups, K=64 in 2 ci-chunks, A row-reuse ----
    f32x4 acc2[4][2];
#pragma unroll
    for (int i = 0; i < 4; ++i) { acc2[i][0] = (f32x4){0.f,0.f,0.f,0.f}; acc2[i][1] = (f32x4){0.f,0.f,0.f,0.f}; }

    for (int c = 0; c < 2; ++c) {
        // h1 writeback for ci-chunk c, layout [cig][px][8] with skewed plane stride
        float bias0 = gB1[unit * 64 + (c * 2) * 16 + l15];
        float bias1 = gB1[unit * 64 + (c * 2 + 1) * 16 + l15];
#pragma unroll
        for (int im = 0; im < 7; ++im) {
            int m = wv + im * 4;
            if (m < 25) {
#pragma unroll
                for (int nn = 0; nn < 2; ++nn) {
                    int n = c * 2 + nn;
                    float bias = nn ? bias1 : bias0;
                    int cig = (nn * 16 + l15) >> 3;
                    int e   = l15 & 7;
#pragma unroll
                    for (int r = 0; r < 4; ++r) {
                        int px = m * 16 + q * 4 + r;
                        int py1 = (px * 205) >> 12;
                        int px1 = px - 20 * py1;
                        int gy = oy0 - 4 + py1, gx = ox0 - 4 + px1;
                        float v = fmaxf(acc1[im][n][r] + bias, 0.f);
                        if (!(gy >= 0 && gy < H && gx >= 0 && gx < W)) v = 0.f;
                        sH1[cig * 3216 + px * 8 + e] = f2us(v);
                    }
                }
            }
        }
        if (c == 0) {   // stage w3 into sIn region (dead after conv1)
            const ushort_t* w3u = w3t + unit * 800;
            for (int i = t; i < 800; i += 256) sW3[i] = w3u[i];
        }
        __syncthreads();

        for (int dx = 0; dx < 5; ++dx) {
            int p = c * 5 + dx;
            const ushort_t* ring = (const ushort_t*)(sRing + (p & 1) * 10240);
            short8 Bf[5][2];
#pragma unroll
            for (int dy = 0; dy < 5; ++dy) {
                Bf[dy][0] = *(const short8*)&ring[dy * 1024 + q * 256 + l15 * 8];
                Bf[dy][1] = *(const short8*)&ring[dy * 1024 + q * 256 + (16 + l15) * 8];
            }
            ldGroup(p + 1);
#pragma unroll
            for (int rel = 0; rel < 8; ++rel) {
                int row = wv * 4 + rel;
                short8 a = *(const short8*)&sH1[q * 3216 + (row * 20 + l15 + dx) * 8];
#pragma unroll
                for (int dy = 0; dy < 5; ++dy) {
                    if (dy >= (rel - 3 < 0 ? 0 : rel - 3) && dy <= (rel < 4 ? rel : 4)) {
                        int im = rel - dy;
                        acc2[im][0] = MFMA16(a, Bf[dy][0], acc2[im][0]);
                        acc2[im][1] = MFMA16(a, Bf[dy][1], acc2[im][1]);
                    }
                }
            }
            wrGroup(p + 1);
            __syncthreads();
        }
    }

    // ---- h2 writeback [cog4][px256][8] into ring region (skewed stride 2064) ----
    {
        float bias0 = gB2[unit * 32 + l15];
        float bias1 = gB2[unit * 32 + 16 + l15];
#pragma unroll
        for (int im = 0; im < 4; ++im) {
            int hy = wv * 4 + im;
#pragma unroll
            for (int n = 0; n < 2; ++n) {
                int co = n * 16 + l15;
                float bias = n ? bias1 : bias0;
                int cog = co >> 3, e = co & 7;
#pragma unroll
                for (int r = 0; r < 4; ++r) {
                    int hx = q * 4 + r;
                    int gy = oy0 - 2 + hy, gx = ox0 - 2 + hx;
                    float v = fmaxf(acc2[im][n][r] + bias, 0.f);
                    if (!(gy >= 0 && gy < H && gx >= 0 && gx < W)) v = 0.f;
                    sH2[cog * 2064 + (hy * 16 + hx) * 8 + e] = f2us(v);
                }
            }
        }
    }
    __syncthreads();

    // ---- conv3: per-tap MFMA, K=32, 9 m-tiles over 144 out px ----
    float b3 = gB3[unit];
    int nm = (wv == 0) ? 3 : 2;
    for (int jm = 0; jm < nm; ++jm) {
        int mt = wv + 4 * jm;                        // 0..8
        int p = mt * 16 + l15;                       // 0..143
        int oy2 = (p * 683) >> 13, ox2 = p - 12 * oy2;
        f32x4 acc = (f32x4){0.f, 0.f, 0.f, 0.f};
        for (int tap = 0; tap < 25; ++tap) {
            int dy = (tap * 13) >> 6, dx = tap - 5 * dy;
            int h2px = (oy2 + dy) * 16 + ox2 + dx;
            short8 a = *(const short8*)&sH2[q * 2064 + h2px * 8];
            short8 w = *(const short8*)&sW3[tap * 32 + q * 8];
            acc = MFMA16(a, w, acc);
        }
        if (l15 == 0) {
#pragma unroll
            for (int r = 0; r < 4; ++r) {
                int pp = mt * 16 + q * 4 + r;
                int oy = (pp * 683) >> 13, ox = pp - 12 * oy;
                int gy = oy0 + oy, gx = ox0 + ox;
                if (gy < H && gx < W) {
                    size_t o = (size_t)b * outW * outH + (size_t)(gy * s2 + ppy) * outW + (gx * s2 + ppx);
                    out[o] = acc[r] + b3;
                }
            }
        }
    }
}

// ---------------------------------------------------------------------------
// MSF input: up4(out_x2) + up2(out_x4) + out_x8 (bilinear, half-pixel, clamped)
// ---------------------------------------------------------------------------
__device__ __forceinline__ void ax_w(int i, float inv_s, int n, int& i0, int& i1, float& w1) {
    float c  = (i + 0.5f) * inv_s - 0.5f;
    float fl = floorf(c);
    w1 = c - fl;
    int ii = (int)fl;
    i0 = ii < 0 ? 0 : ii;
    i1 = (ii + 1 >= n) ? (n - 1) : (ii + 1);
}

__global__ __launch_bounds__(256) void msf_in_kernel(
    const float* __restrict__ f2, const float* __restrict__ f4,
    const float* __restrict__ f8, float* __restrict__ dst)
{
    int idx = blockIdx.x * 256 + threadIdx.x;   // 4*512*512
    int x = idx & 511;
    int y = (idx >> 9) & 511;
    int b = idx >> 18;

    int y0, y1, x0, x1;
    float wy, wx;

    ax_w(y, 0.25f, 128, y0, y1, wy);
    ax_w(x, 0.25f, 128, x0, x1, wx);
    const float* p2 = f2 + (size_t)b * 16384;
    float v4 = (1.f - wy) * ((1.f - wx) * p2[y0 * 128 + x0] + wx * p2[y0 * 128 + x1])
             +        wy  * ((1.f - wx) * p2[y1 * 128 + x0] + wx * p2[y1 * 128 + x1]);

    ax_w(y, 0.5f, 256, y0, y1, wy);
    ax_w(x, 0.5f, 256, x0, x1, wx);
    const float* p4 = f4 + (size_t)b * 65536;
    float v2 = (1.f - wy) * ((1.f - wx) * p4[y0 * 256 + x0] + wx * p4[y0 * 256 + x1])
             +        wy  * ((1.f - wx) * p4[y1 * 256 + x0] + wx * p4[y1 * 256 + x1]);

    dst[idx] = v4 + v2 + f8[idx];
}

// ---------------------------------------------------------------------------
extern "C" void kernel_launch(void* const* d_in, const int* in_sizes, int n_in,
                              void* d_out, int out_size, void* d_ws, size_t ws_size,
                              hipStream_t stream)
{
    (void)in_sizes; (void)n_in; (void)out_size; (void)ws_size;

    const float* image = (const float*)d_in[0];
    const float* W1    = (const float*)d_in[1];
    const float* B1    = (const float*)d_in[2];
    const float* W2    = (const float*)d_in[3];
    const float* B2    = (const float*)d_in[4];
    const float* W3    = (const float*)d_in[5];
    const float* B3    = (const float*)d_in[6];

    float* out = (float*)d_out;
    float* o2 = out;                 // (4,1,128,128)
    float* o4 = out + 65536;         // (4,1,256,256)
    float* o8 = out + 327680;        // (4,1,512,512)
    float* om = out + 1376256;       // msf (4,1,512,512)

    float*    fm  = (float*)d_ws;                              // 4 MB
    ushort_t* w1t = (ushort_t*)((char*)d_ws + 4194304);        // 79872 u16
    ushort_t* w2t = (ushort_t*)((char*)d_ws + 4354048);        // 665600 u16
    ushort_t* w3t = (ushort_t*)((char*)d_ws + 5685248);        // 10400 u16

    prep_weights<<<2600, 256, 0, stream>>>(W1, W2, W3, w1t, w2t, w3t);

    srcnn_mfma<<<dim3(6, 6, 16), 256, 0, stream>>>(
        image, 64, 64, w1t, w2t, w3t, B1, B2, B3, 0, o2, 2);
    srcnn_mfma<<<dim3(11, 11, 16), 256, 0, stream>>>(
        o2, 128, 128, w1t, w2t, w3t, B1, B2, B3, 4, o4, 2);
    srcnn_mfma<<<dim3(22, 22, 16), 256, 0, stream>>>(
        o4, 256, 256, w1t, w2t, w3t, B1, B2, B3, 8, o8, 2);
    msf_in_kernel<<<4096, 256, 0, stream>>>(o2, o4, o8, fm);
    srcnn_mfma<<<dim3(43, 43, 4), 256, 0, stream>>>(
        fm, 512, 512, w1t, w2t, w3t, B1, B2, B3, 12, om, 1);
}

// Round 6
// 1961.534 us; speedup vs baseline: 30.9308x; 1.0650x over previous
//
#include <hip/hip_runtime.h>

// DSDMSR_x8: 13-unit SRCNN cascade, fp32 I/O, bf16 MFMA compute.
// Per 12x12 output tile (256 thr / 4 waves; __launch_bounds__(256,3) targets
// 3 waves/SIMD by keeping peak VGPR+AGPR <= ~168):
//   conv1 9x9 1->64 : split into 2 ci-half passes (acc 56 AGPR each), A-frags
//                     built in registers from sIn, B reloaded per kc (8 regs)
//   conv2 5x5 64->32: dx-major tap groups, K=64 in 2 ci-chunks; B staged
//                     global->VGPR->LDS ring (double-buffered)
//   conv3 5x5 32->1 : per-tap MFMA (K=32), col 0 of C stored
// LDS 49344 B: sH1 4x3216sh | ring 2x10240 (union h2 4x2064sh) | sIn/sW3

typedef unsigned short ushort_t;
typedef __attribute__((ext_vector_type(8))) short short8;   // 8 bf16
typedef __attribute__((ext_vector_type(4))) float f32x4;
typedef __attribute__((ext_vector_type(4))) unsigned int uint4v;

__device__ __forceinline__ float us2f(ushort_t u) { return __uint_as_float(((unsigned int)u) << 16); }
__device__ __forceinline__ ushort_t f2us(float f) {
    unsigned int x = __float_as_uint(f);
    return (ushort_t)((x + 0x7fffu + ((x >> 16) & 1u)) >> 16);
}

#define MFMA16(a, b, c) __builtin_amdgcn_mfma_f32_16x16x32_bf16((a), (b), (c), 0, 0, 0)

// ---------------------------------------------------------------------------
// Weight prep (bf16, MFMA-fragment-friendly layouts):
//  w1t [u][kc3][cig4][ch64][8]          (k = kc*32+cig*8+e, zero for k>=81)
//  w2t [u][c2][dx5][dy5][cig4][co32][8] (ci = c*32+cig*8+e, tap = dy*5+dx)
//  w3t [u][tap25][ci32]
// ---------------------------------------------------------------------------
__global__ __launch_bounds__(256) void prep_weights(
    const float* __restrict__ W1, const float* __restrict__ W2, const float* __restrict__ W3,
    ushort_t* __restrict__ w1t, ushort_t* __restrict__ w2t, ushort_t* __restrict__ w3t)
{
    int i = blockIdx.x * 256 + threadIdx.x;
    if (i < 13 * 3 * 4 * 64 * 8) {           // 79872
        int e = i & 7, ch = (i >> 3) & 63, cig = (i >> 9) & 3;
        int r = i >> 11;                     // u*3 + kc
        int kc = r % 3, u = r / 3;
        int k = kc * 32 + cig * 8 + e;
        w1t[i] = (k < 81) ? f2us(W1[(u * 64 + ch) * 81 + k]) : (ushort_t)0;
    }
    if (i < 665600) {                        // 13*2*25*4*32*8
        int e = i & 7, co = (i >> 3) & 31, cig = (i >> 8) & 3;
        int r = i >> 10;                     // (u*2+c)*25 + s, s = dx*5+dy
        int s = r % 25, cc = r / 25;
        int dx = s / 5, dy = s - 5 * dx;
        int c = cc & 1, u = cc >> 1;
        int tap = dy * 5 + dx;
        int ci = c * 32 + cig * 8 + e;
        w2t[i] = f2us(W2[((u * 32 + co) * 64 + ci) * 25 + tap]);
    }
    if (i < 13 * 25 * 32) {                  // 10400
        int ci = i & 31, r = i >> 5;
        int tap = r % 25, u = r / 25;
        w3t[i] = f2us(W3[(u * 32 + ci) * 25 + tap]);
    }
}

// ---------------------------------------------------------------------------
__global__ __launch_bounds__(256, 3) void srcnn_mfma(
    const float* __restrict__ in, int H, int W,
    const ushort_t* __restrict__ w1t, const ushort_t* __restrict__ w2t,
    const ushort_t* __restrict__ w3t,
    const float* __restrict__ gB1, const float* __restrict__ gB2,
    const float* __restrict__ gB3,
    int unitBase, float* __restrict__ out, int s2)
{
    __shared__ __align__(16) char smem[49344];
    ushort_t* sH1  = (ushort_t*)smem;             // 4 planes x 3216 shorts (16-short skew pad)
    char*     sRing = smem + 25728;               // 2 x 10240 B  (union: h2 4 x 2064 shorts)
    float*    sIn  = (float*)(smem + 46208);      // 784 f32 (conv1 only)
    ushort_t* sW3  = (ushort_t*)(smem + 46208);   // 800 u16 (after conv1)
    ushort_t* sH2  = (ushort_t*)sRing;

    const int t = threadIdx.x, lane = t & 63, wv = t >> 6;
    const int q = lane >> 4, l15 = lane & 15;
    const int z = blockIdx.z;
    const int k4 = (s2 == 2) ? (z >> 2) : 0;
    const int b  = (s2 == 2) ? (z & 3)  : z;
    const int unit = unitBase + k4;
    const int ppx = k4 & 1, ppy = k4 >> 1;
    const int ox0 = blockIdx.x * 12, oy0 = blockIdx.y * 12;
    const int outW = W * s2;
    const int outH = H * s2;
    const float* inb = in + (size_t)b * H * W;

    const char* w2u = (const char*)w2t + (size_t)unit * 102400;

    // --- conv2 B staging: global -> VGPR (pf) -> LDS ring slot p&1 ---
    uint4v pf[3];
    auto ldGroup = [&](int p) {
        if (p < 10) {
            const char* src = w2u + (size_t)p * 10240 + lane * 16;
#pragma unroll
            for (int j = 0; j < 3; ++j) {
                int ck = wv + j * 4;
                if (ck < 10) pf[j] = *(const uint4v*)(src + ck * 1024);
            }
        }
    };
    auto wrGroup = [&](int p) {
        if (p < 10) {
            char* dst = sRing + (p & 1) * 10240 + lane * 16;
#pragma unroll
            for (int j = 0; j < 3; ++j) {
                int ck = wv + j * 4;
                if (ck < 10) *(uint4v*)(dst + ck * 1024) = pf[j];
            }
        }
    };

    ldGroup(0);

    // stage input 28x28 (origin -8, zero-padded)
    for (int idx = t; idx < 784; idx += 256) {
        int y = idx / 28, x = idx - 28 * y;
        int gy = oy0 - 8 + y, gx = ox0 - 8 + x;
        sIn[idx] = (gy >= 0 && gy < H && gx >= 0 && gx < W) ? inb[(size_t)gy * W + gx] : 0.f;
    }
    __syncthreads();
    wrGroup(0);   // barrier drained vmcnt; frees pf before conv1

    const ushort_t* w1u = w1t + (size_t)unit * (3 * 4 * 64 * 8);

    f32x4 acc2[4][2];
#pragma unroll
    for (int i = 0; i < 4; ++i) { acc2[i][0] = (f32x4){0.f,0.f,0.f,0.f}; acc2[i][1] = (f32x4){0.f,0.f,0.f,0.f}; }

    for (int c = 0; c < 2; ++c) {
        // ---- conv1 half: h1 channels [c*32, c*32+32), kc-outer to minimize regs ----
        f32x4 acc1h[7][2];
#pragma unroll
        for (int i = 0; i < 7; ++i) { acc1h[i][0] = (f32x4){0.f,0.f,0.f,0.f}; acc1h[i][1] = (f32x4){0.f,0.f,0.f,0.f}; }

        for (int kc = 0; kc < 3; ++kc) {
            short8 bh0 = *(const short8*)&w1u[((kc * 4 + q) * 64 + (c * 32 + l15)) * 8];
            short8 bh1 = *(const short8*)&w1u[((kc * 4 + q) * 64 + (c * 32 + 16 + l15)) * 8];
            int toff8[8];
#pragma unroll
            for (int j = 0; j < 8; ++j) {
                int k = kc * 32 + q * 8 + j;
                if (k < 81) { int ty = (k * 57) >> 9; toff8[j] = ty * 28 + (k - 9 * ty); }
                else toff8[j] = -1;
            }
#pragma unroll
            for (int im = 0; im < 7; ++im) {
                int m = wv + im * 4;
                if (m < 25) {
                    int px = m * 16 + l15;                    // 0..399 (20x20 h1 grid)
                    int py1 = (px * 205) >> 12;
                    int base = py1 * 28 + (px - 20 * py1);
                    union { short8 v; ushort_t u[8]; } a;
#pragma unroll
                    for (int j = 0; j < 8; ++j) {
                        int o = toff8[j];
                        a.u[j] = (o >= 0) ? f2us(sIn[base + o]) : (ushort_t)0;
                    }
                    acc1h[im][0] = MFMA16(a.v, bh0, acc1h[im][0]);
                    acc1h[im][1] = MFMA16(a.v, bh1, acc1h[im][1]);
                }
            }
        }

        // ---- h1 writeback for this half, layout [cig][px][8], skewed planes ----
        float bias0 = gB1[unit * 64 + c * 32 + l15];
        float bias1 = gB1[unit * 64 + c * 32 + 16 + l15];
#pragma unroll
        for (int im = 0; im < 7; ++im) {
            int m = wv + im * 4;
            if (m < 25) {
#pragma unroll
                for (int nn = 0; nn < 2; ++nn) {
                    float bias = nn ? bias1 : bias0;
                    int cig = (nn * 16 + l15) >> 3;
                    int e   = l15 & 7;
#pragma unroll
                    for (int r = 0; r < 4; ++r) {
                        int px = m * 16 + q * 4 + r;
                        int py1 = (px * 205) >> 12;
                        int px1 = px - 20 * py1;
                        int gy = oy0 - 4 + py1, gx = ox0 - 4 + px1;
                        float v = fmaxf(acc1h[im][nn][r] + bias, 0.f);
                        if (!(gy >= 0 && gy < H && gx >= 0 && gx < W)) v = 0.f;
                        sH1[cig * 3216 + px * 8 + e] = f2us(v);
                    }
                }
            }
        }
        __syncthreads();

        // ---- conv2: dx-major groups, A row-reuse across dy ----
        for (int dx = 0; dx < 5; ++dx) {
            int p = c * 5 + dx;
            const ushort_t* ring = (const ushort_t*)(sRing + (p & 1) * 10240);
            short8 Bf[5][2];
#pragma unroll
            for (int dy = 0; dy < 5; ++dy) {
                Bf[dy][0] = *(const short8*)&ring[dy * 1024 + q * 256 + l15 * 8];
                Bf[dy][1] = *(const short8*)&ring[dy * 1024 + q * 256 + (16 + l15) * 8];
            }
            ldGroup(p + 1);
#pragma unroll
            for (int rel = 0; rel < 8; ++rel) {
                int row = wv * 4 + rel;
                short8 a = *(const short8*)&sH1[q * 3216 + (row * 20 + l15 + dx) * 8];
#pragma unroll
                for (int dy = 0; dy < 5; ++dy) {
                    if (dy >= (rel - 3 < 0 ? 0 : rel - 3) && dy <= (rel < 4 ? rel : 4)) {
                        int im = rel - dy;
                        acc2[im][0] = MFMA16(a, Bf[dy][0], acc2[im][0]);
                        acc2[im][1] = MFMA16(a, Bf[dy][1], acc2[im][1]);
                    }
                }
            }
            wrGroup(p + 1);
            __syncthreads();
        }
    }

    // ---- h2 writeback [cog4][px256][8] into ring region (skewed stride 2064) ----
    {
        float bias0 = gB2[unit * 32 + l15];
        float bias1 = gB2[unit * 32 + 16 + l15];
#pragma unroll
        for (int im = 0; im < 4; ++im) {
            int hy = wv * 4 + im;
#pragma unroll
            for (int n = 0; n < 2; ++n) {
                int co = n * 16 + l15;
                float bias = n ? bias1 : bias0;
                int cog = co >> 3, e = co & 7;
#pragma unroll
                for (int r = 0; r < 4; ++r) {
                    int hx = q * 4 + r;
                    int gy = oy0 - 2 + hy, gx = ox0 - 2 + hx;
                    float v = fmaxf(acc2[im][n][r] + bias, 0.f);
                    if (!(gy >= 0 && gy < H && gx >= 0 && gx < W)) v = 0.f;
                    sH2[cog * 2064 + (hy * 16 + hx) * 8 + e] = f2us(v);
                }
            }
        }
    }
    // stage w3 into sIn region (dead after conv1 half 2)
    {
        const ushort_t* w3u = w3t + unit * 800;
        for (int i = t; i < 800; i += 256) sW3[i] = w3u[i];
    }
    __syncthreads();

    // ---- conv3: per-tap MFMA, K=32, 9 m-tiles over 144 out px ----
    float b3 = gB3[unit];
    int nm = (wv == 0) ? 3 : 2;
    for (int jm = 0; jm < nm; ++jm) {
        int mt = wv + 4 * jm;                        // 0..8
        int p = mt * 16 + l15;                       // 0..143
        int oy2 = (p * 683) >> 13, ox2 = p - 12 * oy2;
        f32x4 acc = (f32x4){0.f, 0.f, 0.f, 0.f};
        for (int tap = 0; tap < 25; ++tap) {
            int dy = (tap * 13) >> 6, dx = tap - 5 * dy;
            int h2px = (oy2 + dy) * 16 + ox2 + dx;
            short8 a = *(const short8*)&sH2[q * 2064 + h2px * 8];
            short8 w = *(const short8*)&sW3[tap * 32 + q * 8];
            acc = MFMA16(a, w, acc);
        }
        if (l15 == 0) {
#pragma unroll
            for (int r = 0; r < 4; ++r) {
                int pp = mt * 16 + q * 4 + r;
                int oy = (pp * 683) >> 13, ox = pp - 12 * oy;
                int gy = oy0 + oy, gx = ox0 + ox;
                if (gy < H && gx < W) {
                    size_t o = (size_t)b * outW * outH + (size_t)(gy * s2 + ppy) * outW + (gx * s2 + ppx);
                    out[o] = acc[r] + b3;
                }
            }
        }
    }
}

// ---------------------------------------------------------------------------
// MSF input: up4(out_x2) + up2(out_x4) + out_x8 (bilinear, half-pixel, clamped)
// ---------------------------------------------------------------------------
__device__ __forceinline__ void ax_w(int i, float inv_s, int n, int& i0, int& i1, float& w1) {
    float c  = (i + 0.5f) * inv_s - 0.5f;
    float fl = floorf(c);
    w1 = c - fl;
    int ii = (int)fl;
    i0 = ii < 0 ? 0 : ii;
    i1 = (ii + 1 >= n) ? (n - 1) : (ii + 1);
}

__global__ __launch_bounds__(256) void msf_in_kernel(
    const float* __restrict__ f2, const float* __restrict__ f4,
    const float* __restrict__ f8, float* __restrict__ dst)
{
    int idx = blockIdx.x * 256 + threadIdx.x;   // 4*512*512
    int x = idx & 511;
    int y = (idx >> 9) & 511;
    int b = idx >> 18;

    int y0, y1, x0, x1;
    float wy, wx;

    ax_w(y, 0.25f, 128, y0, y1, wy);
    ax_w(x, 0.25f, 128, x0, x1, wx);
    const float* p2 = f2 + (size_t)b * 16384;
    float v4 = (1.f - wy) * ((1.f - wx) * p2[y0 * 128 + x0] + wx * p2[y0 * 128 + x1])
             +        wy  * ((1.f - wx) * p2[y1 * 128 + x0] + wx * p2[y1 * 128 + x1]);

    ax_w(y, 0.5f, 256, y0, y1, wy);
    ax_w(x, 0.5f, 256, x0, x1, wx);
    const float* p4 = f4 + (size_t)b * 65536;
    float v2 = (1.f - wy) * ((1.f - wx) * p4[y0 * 256 + x0] + wx * p4[y0 * 256 + x1])
             +        wy  * ((1.f - wx) * p4[y1 * 256 + x0] + wx * p4[y1 * 256 + x1]);

    dst[idx] = v4 + v2 + f8[idx];
}

// ---------------------------------------------------------------------------
extern "C" void kernel_launch(void* const* d_in, const int* in_sizes, int n_in,
                              void* d_out, int out_size, void* d_ws, size_t ws_size,
                              hipStream_t stream)
{
    (void)in_sizes; (void)n_in; (void)out_size; (void)ws_size;

    const float* image = (const float*)d_in[0];
    const float* W1    = (const float*)d_in[1];
    const float* B1    = (const float*)d_in[2];
    const float* W2    = (const float*)d_in[3];
    const float* B2    = (const float*)d_in[4];
    const float* W3    = (const float*)d_in[5];
    const float* B3    = (const float*)d_in[6];

    float* out = (float*)d_out;
    float* o2 = out;                 // (4,1,128,128)
    float* o4 = out + 65536;         // (4,1,256,256)
    float* o8 = out + 327680;        // (4,1,512,512)
    float* om = out + 1376256;       // msf (4,1,512,512)

    float*    fm  = (float*)d_ws;                              // 4 MB
    ushort_t* w1t = (ushort_t*)((char*)d_ws + 4194304);        // 79872 u16
    ushort_t* w2t = (ushort_t*)((char*)d_ws + 4354048);        // 665600 u16
    ushort_t* w3t = (ushort_t*)((char*)d_ws + 5685248);        // 10400 u16

    prep_weights<<<2600, 256, 0, stream>>>(W1, W2, W3, w1t, w2t, w3t);

    srcnn_mfma<<<dim3(6, 6, 16), 256, 0, stream>>>(
        image, 64, 64, w1t, w2t, w3t, B1, B2, B3, 0, o2, 2);
    srcnn_mfma<<<dim3(11, 11, 16), 256, 0, stream>>>(
        o2, 128, 128, w1t, w2t, w3t, B1, B2, B3, 4, o4, 2);
    srcnn_mfma<<<dim3(22, 22, 16), 256, 0, stream>>>(
        o4, 256, 256, w1t, w2t, w3t, B1, B2, B3, 8, o8, 2);
    msf_in_kernel<<<4096, 256, 0, stream>>>(o2, o4, o8, fm);
    srcnn_mfma<<<dim3(43, 43, 4), 256, 0, stream>>>(
        fm, 512, 512, w1t, w2t, w3t, B1, B2, B3, 12, om, 1);
}